// Round 1
// baseline (112.437 us; speedup 1.0000x reference)
//
#include <hip/hip_runtime.h>

// entmax-1.5 over last axis (K=256) of [2048,127,256] fp32.
// tau* is the root of f(tau) = sum relu(z - tau)^2 - 1 (z = logits/2),
// bracketed in [max(z)-1, max(z)]. 16 bisection steps -> |dtau| <= 2^-16,
// output err ~3e-5 << 2e-2 threshold. No sort needed.
//
// Layout: 8 lanes/row, 32 elems/lane in VGPRs, 8 rows/wave, 4 waves/block
// -> 32 rows/block, 260096 rows = 8128 blocks exactly.

#define K 256
#define LANES_PER_ROW 8
#define ELEMS_PER_LANE 32   // K / LANES_PER_ROW
#define ROWS_PER_WAVE 8
#define NITER 16

__global__ __launch_bounds__(256) void entmax15_kernel(
    const float* __restrict__ in, float* __restrict__ out, int nrows)
{
    const int lane = threadIdx.x & 63;
    const int wave_in_blk = threadIdx.x >> 6;
    const int sub  = lane & (LANES_PER_ROW - 1);   // lane within row
    const int rloc = lane >> 3;                    // row within wave
    const long long row =
        ((long long)blockIdx.x * 4 + wave_in_blk) * ROWS_PER_WAVE + rloc;
    if (row >= nrows) return;

    const float* rp = in + row * K + sub * 4;

    // load 32 elems/lane as 8x float4, scale by 0.5 (x = logits/2)
    float z[ELEMS_PER_LANE];
    #pragma unroll
    for (int k = 0; k < 8; ++k) {
        const float4 v = *reinterpret_cast<const float4*>(rp + k * 32);
        z[k*4+0] = v.x * 0.5f;
        z[k*4+1] = v.y * 0.5f;
        z[k*4+2] = v.z * 0.5f;
        z[k*4+3] = v.w * 0.5f;
    }

    // row max (no explicit max-subtraction: fold into tau bracket)
    float m = z[0];
    #pragma unroll
    for (int i = 1; i < ELEMS_PER_LANE; ++i) m = fmaxf(m, z[i]);
    m = fmaxf(m, __shfl_xor(m, 1, 64));
    m = fmaxf(m, __shfl_xor(m, 2, 64));
    m = fmaxf(m, __shfl_xor(m, 4, 64));

    // bisection on f(tau) = sum relu(z - tau)^2 - 1, tau in [m-1, m]
    float lo = m - 1.0f;
    float hi = m;
    for (int it = 0; it < NITER; ++it) {
        const float tau = 0.5f * (lo + hi);
        float a0 = 0.0f, a1 = 0.0f, a2 = 0.0f, a3 = 0.0f;
        #pragma unroll
        for (int i = 0; i < ELEMS_PER_LANE; i += 4) {
            const float d0 = fmaxf(z[i+0] - tau, 0.0f);
            const float d1 = fmaxf(z[i+1] - tau, 0.0f);
            const float d2 = fmaxf(z[i+2] - tau, 0.0f);
            const float d3 = fmaxf(z[i+3] - tau, 0.0f);
            a0 = fmaf(d0, d0, a0);
            a1 = fmaf(d1, d1, a1);
            a2 = fmaf(d2, d2, a2);
            a3 = fmaf(d3, d3, a3);
        }
        float f = (a0 + a1) + (a2 + a3);
        f += __shfl_xor(f, 1, 64);
        f += __shfl_xor(f, 2, 64);
        f += __shfl_xor(f, 4, 64);
        const bool gt = (f > 1.0f);   // f(tau) > 0 -> root is right of tau
        lo = gt ? tau : lo;
        hi = gt ? hi  : tau;
    }
    const float tau = 0.5f * (lo + hi);

    // y = relu(z - tau)^2, stored as 8x float4
    float* op = out + row * K + sub * 4;
    #pragma unroll
    for (int k = 0; k < 8; ++k) {
        const float d0 = fmaxf(z[k*4+0] - tau, 0.0f);
        const float d1 = fmaxf(z[k*4+1] - tau, 0.0f);
        const float d2 = fmaxf(z[k*4+2] - tau, 0.0f);
        const float d3 = fmaxf(z[k*4+3] - tau, 0.0f);
        float4 v;
        v.x = d0 * d0;
        v.y = d1 * d1;
        v.z = d2 * d2;
        v.w = d3 * d3;
        *reinterpret_cast<float4*>(op + k * 32) = v;
    }
}

extern "C" void kernel_launch(void* const* d_in, const int* in_sizes, int n_in,
                              void* d_out, int out_size, void* d_ws, size_t ws_size,
                              hipStream_t stream)
{
    const float* in = (const float*)d_in[0];
    float* out = (float*)d_out;
    const int nrows = in_sizes[0] / K;                 // 260096
    const int rows_per_block = 4 * ROWS_PER_WAVE;      // 32
    const int blocks = (nrows + rows_per_block - 1) / rows_per_block;  // 8128
    entmax15_kernel<<<dim3(blocks), dim3(256), 0, stream>>>(in, out, nrows);
}

// Round 2
// 107.491 us; speedup vs baseline: 1.0460x; 1.0460x over previous
//
#include <hip/hip_runtime.h>

// entmax-1.5 over last axis (K=256) of [2048,127,256] fp32.
//
// Work in raw-x domain: with z = x/2, tau = t/2, solving
//   g(t) = sum relu(x - t)^2 = 4  is equivalent, and y = (relu(x-t)/2)^2.
// g is convex, piecewise-quadratic, monotone decreasing; Newton from
// t0 = max(x) - 2 (where g >= 4) converges monotonically from the left,
// never overshoots, quadratically near the root. 6 iterations << 16
// bisections of the previous round, cutting VALU issue ~2x.
//
// Layout: 8 lanes/row (32 elems/lane in VGPRs), 8 rows/wave, 4 waves/block
// -> 32 rows/block; 260096 rows = 8128 blocks exactly (no tail, no guard).

#define K 256
#define NITER 6

__global__ __launch_bounds__(256) void entmax15_kernel(
    const float* __restrict__ in, float* __restrict__ out)
{
    const int lane = threadIdx.x & 63;
    const int wave = threadIdx.x >> 6;
    const int sub  = lane & 7;        // lane within row (8 lanes/row)
    const int rloc = lane >> 3;       // row within wave
    const long long row = ((long long)blockIdx.x * 4 + wave) * 8 + rloc;

    const float* rp = in + row * (long long)K + sub * 4;

    // 32 elems/lane as 8x float4 (raw x, no scaling)
    float x[32];
    #pragma unroll
    for (int k = 0; k < 8; ++k) {
        const float4 v = *reinterpret_cast<const float4*>(rp + k * 32);
        x[k*4+0] = v.x; x[k*4+1] = v.y; x[k*4+2] = v.z; x[k*4+3] = v.w;
    }

    // row max: per-lane pairwise tree + 3 shuffle rounds across the 8 lanes
    float m0 = fmaxf(x[0], x[1]);
    float m1 = fmaxf(x[2], x[3]);
    float m2 = fmaxf(x[4], x[5]);
    float m3 = fmaxf(x[6], x[7]);
    #pragma unroll
    for (int i = 8; i < 32; i += 4) {
        m0 = fmaxf(m0, x[i+0]);
        m1 = fmaxf(m1, x[i+1]);
        m2 = fmaxf(m2, x[i+2]);
        m3 = fmaxf(m3, x[i+3]);
    }
    float m = fmaxf(fmaxf(m0, m1), fmaxf(m2, m3));
    m = fmaxf(m, __shfl_xor(m, 1, 64));
    m = fmaxf(m, __shfl_xor(m, 2, 64));
    m = fmaxf(m, __shfl_xor(m, 4, 64));

    // Newton on g(t) = sum relu(x-t)^2 - 4, g'(t) = -2 sum relu(x-t).
    // t <= t* throughout; s1 > 0 always (max element keeps d = m - t > 0).
    float t = m - 2.0f;
    #pragma unroll
    for (int it = 0; it < NITER; ++it) {
        float s1a = 0.0f, s1b = 0.0f, s2a = 0.0f, s2b = 0.0f;
        #pragma unroll
        for (int i = 0; i < 32; i += 2) {
            const float d0 = fmaxf(x[i]   - t, 0.0f);
            const float d1 = fmaxf(x[i+1] - t, 0.0f);
            s1a += d0;
            s1b += d1;
            s2a = fmaf(d0, d0, s2a);
            s2b = fmaf(d1, d1, s2b);
        }
        float s1 = s1a + s1b;
        float s2 = s2a + s2b;
        s1 += __shfl_xor(s1, 1, 64);
        s2 += __shfl_xor(s2, 1, 64);
        s1 += __shfl_xor(s1, 2, 64);
        s2 += __shfl_xor(s2, 2, 64);
        s1 += __shfl_xor(s1, 4, 64);
        s2 += __shfl_xor(s2, 4, 64);
        t += (s2 - 4.0f) * 0.5f * __builtin_amdgcn_rcpf(s1);
    }

    // y = (relu(x - t) / 2)^2
    float* op = out + row * (long long)K + sub * 4;
    #pragma unroll
    for (int k = 0; k < 8; ++k) {
        const float d0 = fmaxf(x[k*4+0] - t, 0.0f) * 0.5f;
        const float d1 = fmaxf(x[k*4+1] - t, 0.0f) * 0.5f;
        const float d2 = fmaxf(x[k*4+2] - t, 0.0f) * 0.5f;
        const float d3 = fmaxf(x[k*4+3] - t, 0.0f) * 0.5f;
        float4 v;
        v.x = d0 * d0;
        v.y = d1 * d1;
        v.z = d2 * d2;
        v.w = d3 * d3;
        *reinterpret_cast<float4*>(op + k * 32) = v;
    }
}

extern "C" void kernel_launch(void* const* d_in, const int* in_sizes, int n_in,
                              void* d_out, int out_size, void* d_ws, size_t ws_size,
                              hipStream_t stream)
{
    const float* in = (const float*)d_in[0];
    float* out = (float*)d_out;
    const int nrows = in_sizes[0] / K;                    // 260096
    const int blocks = nrows / 32;                        // 8128, exact
    entmax15_kernel<<<dim3(blocks), dim3(256), 0, stream>>>(in, out);
}

// Round 4
// 89.319 us; speedup vs baseline: 1.2588x; 1.2035x over previous
//
#include <hip/hip_runtime.h>

// entmax-1.5 over last axis (K=256) of [2048,127,256] fp32.
//
// Math (unchanged from R2, verified absmax 3.9e-3 vs 2e-2 threshold):
// with z = x/2, tau = t/2: solve g(t) = sum relu(x-t)^2 = 4 by Newton from
// t0 = max(x)-2 (convex, monotone -> no overshoot), y = (relu(x-t)/2)^2.
//
// R3/R4: software-pipelined persistent waves. R2 showed neither VALU-bound
// (~29 us issue) nor at the memory floor (84.5 us) -- 107.5 us = 79% of
// copy BW. Theory: convoy effect -- waves phase-lock in {load / wait /
// long compute / store} so the memory pipe idles during the collective
// compute phase. Fix: each wave owns 8 row batches, double-buffered in
// registers: while solving batch i, batch i+1's loads are in flight.
// R4 fixes the compile error: __builtin_nontemporal_store needs a clang
// ext_vector_type, not HIP's float4 class.
//
// Layout: 8 lanes/row, 32 elems/lane, 8 rows/batch/wave, 4 waves/block.
// 260096 rows = 1016 blocks x 4 waves x 8 batches x 8 rows (exact).

#define K 256
#define NITER 6
#define BATCHES 8

typedef float vf4 __attribute__((ext_vector_type(4)));

__device__ __forceinline__ void load_batch(const float* __restrict__ p,
                                           float x[32]) {
    #pragma unroll
    for (int k = 0; k < 8; ++k) {
        const vf4 v = *reinterpret_cast<const vf4*>(p + k * 32);
        x[k*4+0] = v.x; x[k*4+1] = v.y; x[k*4+2] = v.z; x[k*4+3] = v.w;
    }
}

__device__ __forceinline__ void solve_store(const float x[32],
                                            float* __restrict__ op) {
    // row max: per-lane tree + 3 shuffle rounds across the row's 8 lanes
    float m0 = fmaxf(x[0], x[1]);
    float m1 = fmaxf(x[2], x[3]);
    float m2 = fmaxf(x[4], x[5]);
    float m3 = fmaxf(x[6], x[7]);
    #pragma unroll
    for (int i = 8; i < 32; i += 4) {
        m0 = fmaxf(m0, x[i+0]);
        m1 = fmaxf(m1, x[i+1]);
        m2 = fmaxf(m2, x[i+2]);
        m3 = fmaxf(m3, x[i+3]);
    }
    float m = fmaxf(fmaxf(m0, m1), fmaxf(m2, m3));
    m = fmaxf(m, __shfl_xor(m, 1, 64));
    m = fmaxf(m, __shfl_xor(m, 2, 64));
    m = fmaxf(m, __shfl_xor(m, 4, 64));

    // Newton on g(t) = sum relu(x-t)^2 - 4, g'(t) = -2 sum relu(x-t)
    float t = m - 2.0f;
    #pragma unroll
    for (int it = 0; it < NITER; ++it) {
        float s1a = 0.0f, s1b = 0.0f, s2a = 0.0f, s2b = 0.0f;
        #pragma unroll
        for (int i = 0; i < 32; i += 2) {
            const float d0 = fmaxf(x[i]   - t, 0.0f);
            const float d1 = fmaxf(x[i+1] - t, 0.0f);
            s1a += d0;
            s1b += d1;
            s2a = fmaf(d0, d0, s2a);
            s2b = fmaf(d1, d1, s2b);
        }
        float s1 = s1a + s1b;
        float s2 = s2a + s2b;
        s1 += __shfl_xor(s1, 1, 64);
        s2 += __shfl_xor(s2, 1, 64);
        s1 += __shfl_xor(s1, 2, 64);
        s2 += __shfl_xor(s2, 2, 64);
        s1 += __shfl_xor(s1, 4, 64);
        s2 += __shfl_xor(s2, 4, 64);
        t += (s2 - 4.0f) * 0.5f * __builtin_amdgcn_rcpf(s1);
    }

    // y = (relu(x - t) / 2)^2, nontemporal stores (write-once stream)
    #pragma unroll
    for (int k = 0; k < 8; ++k) {
        const float d0 = fmaxf(x[k*4+0] - t, 0.0f) * 0.5f;
        const float d1 = fmaxf(x[k*4+1] - t, 0.0f) * 0.5f;
        const float d2 = fmaxf(x[k*4+2] - t, 0.0f) * 0.5f;
        const float d3 = fmaxf(x[k*4+3] - t, 0.0f) * 0.5f;
        vf4 v;
        v.x = d0 * d0;
        v.y = d1 * d1;
        v.z = d2 * d2;
        v.w = d3 * d3;
        __builtin_nontemporal_store(v, reinterpret_cast<vf4*>(op + k * 32));
    }
}

__global__ __launch_bounds__(256) void entmax15_kernel(
    const float* __restrict__ in, float* __restrict__ out, int nwaves)
{
    const int lane = threadIdx.x & 63;
    const int wave = threadIdx.x >> 6;
    const int sub  = lane & 7;        // lane within row
    const int rloc = lane >> 3;       // row within batch
    const int g    = blockIdx.x * 4 + wave;

    const long long base    = ((long long)g * 8 + rloc) * K + sub * 4;
    const long long bstride = (long long)nwaves * 8 * K;  // elems per batch step

    float xA[32], xB[32];
    load_batch(in + base, xA);                        // batch 0

    #pragma unroll
    for (int bb = 0; bb < BATCHES / 2; ++bb) {
        const long long offA = base + (long long)(2 * bb)     * bstride;
        const long long offB = base + (long long)(2 * bb + 1) * bstride;
        load_batch(in + offB, xB);                    // prefetch odd batch
        solve_store(xA, out + offA);                  // solve even batch
        if (bb < BATCHES / 2 - 1)
            load_batch(in + offA + 2 * bstride, xA);  // prefetch next even
        solve_store(xB, out + offB);                  // solve odd batch
    }
}

extern "C" void kernel_launch(void* const* d_in, const int* in_sizes, int n_in,
                              void* d_out, int out_size, void* d_ws, size_t ws_size,
                              hipStream_t stream)
{
    const float* in = (const float*)d_in[0];
    float* out = (float*)d_out;
    const int nrows  = in_sizes[0] / K;              // 260096
    const int nwaves = nrows / (8 * BATCHES);        // 4064
    const int blocks = nwaves / 4;                   // 1016
    entmax15_kernel<<<dim3(blocks), dim3(256), 0, stream>>>(in, out, nwaves);
}